// Round 1
// baseline (441.970 us; speedup 1.0000x reference)
//
#include <hip/hip_runtime.h>
#include <hip/hip_bf16.h>
#include <math.h>

#define LTOK 512
#define DDIM 512
#define NEXP 32
#define HDIM 512

// ws layout (bytes):
//   [0, 128)                  cnt: 32 ints
//   [256, 256+65536)          alist: 32*512 ints (assignment id = 2*token+k)
//   [65792, 65792+65536)      slist: 32*512 floats (weight * per_expert_scale)
//   [131584, 131584+2097152)  act: 1024 x 512 floats
// total ~2.13 MB

__device__ __forceinline__ float gelu_tanh(float v) {
    float v3 = v * v * v;
    float inner = 0.7978845608028654f * (v + 0.044715f * v3);
    return 0.5f * v * (1.0f + tanhf(inner));
}

__global__ __launch_bounds__(64) void router_kernel(
    const float* __restrict__ x, const float* __restrict__ rs,
    const float* __restrict__ Wr, const float* __restrict__ pes,
    int* __restrict__ cnt, int* __restrict__ alist, float* __restrict__ slist)
{
    const int t = blockIdx.x;
    const int lane = threadIdx.x;

    float xv[8];
    float ss = 0.f;
#pragma unroll
    for (int j = 0; j < 8; ++j) {
        xv[j] = x[t * DDIM + j * 64 + lane];
        ss += xv[j] * xv[j];
    }
#pragma unroll
    for (int o = 32; o > 0; o >>= 1) ss += __shfl_xor(ss, o);
    const float var = ss * (1.0f / 512.0f);
    const float coef = rsqrtf(var + 1e-6f) * rsqrtf(512.0f);

    __shared__ float ri[DDIM];
#pragma unroll
    for (int j = 0; j < 8; ++j) {
        const int d = j * 64 + lane;
        ri[d] = xv[j] * coef * rs[d];
    }
    __syncthreads();

    // logits: lane&31 -> expert, lane>>5 -> half of D
    const int e = lane & 31;
    const int half = lane >> 5;
    float lg = 0.f;
    const int dbeg = half * 256;
    for (int d = dbeg; d < dbeg + 256; ++d)
        lg = fmaf(ri[d], Wr[d * NEXP + e], lg);
    lg += __shfl_xor(lg, 32);

    __shared__ float lgs[NEXP];
    if (lane < 32) lgs[lane] = lg;
    __syncthreads();

    if (lane == 0) {
        int i0 = 0; float m0 = lgs[0];
        for (int i = 1; i < NEXP; ++i) if (lgs[i] > m0) { m0 = lgs[i]; i0 = i; }
        int i1 = -1; float m1 = -1e30f;
        for (int i = 0; i < NEXP; ++i) if (i != i0 && lgs[i] > m1) { m1 = lgs[i]; i1 = i; }
        // softmax denominator cancels in probs/renorm: weights depend only on top-2 logits
        const float e1 = expf(m1 - m0);
        const float inv = 1.0f / (1.0f + e1);
        const float w0 = inv, w1 = e1 * inv;

        int p0 = atomicAdd(&cnt[i0], 1);
        alist[i0 * LTOK + p0] = t * 2;
        slist[i0 * LTOK + p0] = w0 * pes[i0];
        int p1 = atomicAdd(&cnt[i1], 1);
        alist[i1 * LTOK + p1] = t * 2 + 1;
        slist[i1 * LTOK + p1] = w1 * pes[i1];
    }
}

// grid (8, 32): blockIdx.x = h-tile (64 h), blockIdx.y = expert
__global__ __launch_bounds__(256) void gates_kernel(
    const float* __restrict__ x, const float* __restrict__ G,
    const int* __restrict__ cnt, const int* __restrict__ alist,
    float* __restrict__ act)
{
    const int e = blockIdx.y;
    const int Ne = cnt[e];
    if (Ne == 0) return;
    const int h0 = blockIdx.x * 64;
    const int tid = threadIdx.x;

    __shared__ float Xs[32][65];
    __shared__ float W0s[64][65];
    __shared__ float W1s[64][65];
    __shared__ int toks[32];

    const int tg = tid >> 5;    // token group 0..7 (4 tokens each)
    const int hp = tid & 31;    // h pair 0..31 (2 h each)

    for (int t0 = 0; t0 < Ne; t0 += 32) {
        if (tid < 32) {
            const int idx = t0 + tid;
            toks[tid] = (idx < Ne) ? alist[e * LTOK + idx] : -1;
        }
        __syncthreads();

        float acc0[4][2] = {{0.f}};
        float acc1[4][2] = {{0.f}};

        for (int kt = 0; kt < DDIM; kt += 64) {
#pragma unroll
            for (int i = tid; i < 32 * 64; i += 256) {
                const int row = i >> 6, col = i & 63;
                const int a = toks[row];
                Xs[row][col] = (a >= 0) ? x[(a >> 1) * DDIM + kt + col] : 0.f;
            }
#pragma unroll
            for (int i = tid; i < 64 * 64; i += 256) {
                const int hh = i >> 6, col = i & 63;
                W0s[hh][col] = G[((size_t)(e * 2 + 0) * HDIM + h0 + hh) * DDIM + kt + col];
                W1s[hh][col] = G[((size_t)(e * 2 + 1) * HDIM + h0 + hh) * DDIM + kt + col];
            }
            __syncthreads();

#pragma unroll 4
            for (int k = 0; k < 64; ++k) {
                float xr[4], w0r[2], w1r[2];
#pragma unroll
                for (int i = 0; i < 4; ++i) xr[i] = Xs[tg * 4 + i][k];
#pragma unroll
                for (int j = 0; j < 2; ++j) {
                    w0r[j] = W0s[hp * 2 + j][k];
                    w1r[j] = W1s[hp * 2 + j][k];
                }
#pragma unroll
                for (int i = 0; i < 4; ++i)
#pragma unroll
                    for (int j = 0; j < 2; ++j) {
                        acc0[i][j] = fmaf(xr[i], w0r[j], acc0[i][j]);
                        acc1[i][j] = fmaf(xr[i], w1r[j], acc1[i][j]);
                    }
            }
            __syncthreads();
        }

#pragma unroll
        for (int i = 0; i < 4; ++i) {
            const int a = toks[tg * 4 + i];
            if (a >= 0) {
#pragma unroll
                for (int j = 0; j < 2; ++j) {
                    const float v = gelu_tanh(acc0[i][j]) * acc1[i][j];
                    act[(size_t)a * HDIM + h0 + hp * 2 + j] = v;
                }
            }
        }
        __syncthreads();
    }
}

// grid (8, 32): blockIdx.x = d-tile (64 d), blockIdx.y = expert
__global__ __launch_bounds__(256) void linear_kernel(
    const float* __restrict__ act, const float* __restrict__ Wl,
    const int* __restrict__ cnt, const int* __restrict__ alist,
    const float* __restrict__ slist, float* __restrict__ out)
{
    const int e = blockIdx.y;
    const int Ne = cnt[e];
    if (Ne == 0) return;
    const int d0 = blockIdx.x * 64;
    const int tid = threadIdx.x;

    __shared__ float As[32][65];
    __shared__ float Bs[64][65];
    __shared__ int toks[32];
    __shared__ float scl[32];

    const int tg = tid >> 5;
    const int dp = tid & 31;

    for (int t0 = 0; t0 < Ne; t0 += 32) {
        if (tid < 32) {
            const int idx = t0 + tid;
            toks[tid] = (idx < Ne) ? alist[e * LTOK + idx] : -1;
            scl[tid] = (idx < Ne) ? slist[e * LTOK + idx] : 0.f;
        }
        __syncthreads();

        float acc[4][2] = {{0.f}};

        for (int kt = 0; kt < HDIM; kt += 64) {
#pragma unroll
            for (int i = tid; i < 32 * 64; i += 256) {
                const int row = i >> 6, col = i & 63;
                const int a = toks[row];
                As[row][col] = (a >= 0) ? act[(size_t)a * HDIM + kt + col] : 0.f;
            }
#pragma unroll
            for (int i = tid; i < 64 * 64; i += 256) {
                const int kr = i >> 6, col = i & 63;
                Bs[kr][col] = Wl[((size_t)e * HDIM + kt + kr) * DDIM + d0 + col];
            }
            __syncthreads();

#pragma unroll 4
            for (int k = 0; k < 64; ++k) {
                float ar[4], br[2];
#pragma unroll
                for (int i = 0; i < 4; ++i) ar[i] = As[tg * 4 + i][k];
#pragma unroll
                for (int j = 0; j < 2; ++j) br[j] = Bs[k][dp * 2 + j];
#pragma unroll
                for (int i = 0; i < 4; ++i)
#pragma unroll
                    for (int j = 0; j < 2; ++j)
                        acc[i][j] = fmaf(ar[i], br[j], acc[i][j]);
            }
            __syncthreads();
        }

#pragma unroll
        for (int i = 0; i < 4; ++i) {
            const int a = toks[tg * 4 + i];
            if (a >= 0) {
                const float s = scl[tg * 4 + i];
#pragma unroll
                for (int j = 0; j < 2; ++j)
                    atomicAdd(&out[(size_t)(a >> 1) * DDIM + d0 + dp * 2 + j], acc[i][j] * s);
            }
        }
        __syncthreads();
    }
}

extern "C" void kernel_launch(void* const* d_in, const int* in_sizes, int n_in,
                              void* d_out, int out_size, void* d_ws, size_t ws_size,
                              hipStream_t stream)
{
    const float* x   = (const float*)d_in[0];
    const float* rs  = (const float*)d_in[1];
    const float* Wr  = (const float*)d_in[2];
    const float* G   = (const float*)d_in[3];
    const float* Wl  = (const float*)d_in[4];
    const float* pes = (const float*)d_in[5];
    float* out = (float*)d_out;

    char* ws = (char*)d_ws;
    int*   cnt   = (int*)(ws);
    int*   alist = (int*)(ws + 256);
    float* slist = (float*)(ws + 256 + 65536);
    float* act   = (float*)(ws + 256 + 65536 + 65536 + 256);

    hipMemsetAsync(cnt, 0, NEXP * sizeof(int), stream);
    hipMemsetAsync(out, 0, (size_t)out_size * sizeof(float), stream);

    router_kernel<<<dim3(LTOK), dim3(64), 0, stream>>>(x, rs, Wr, pes, cnt, alist, slist);
    gates_kernel<<<dim3(8, NEXP), dim3(256), 0, stream>>>(x, G, cnt, alist, act);
    linear_kernel<<<dim3(8, NEXP), dim3(256), 0, stream>>>(act, Wl, cnt, alist, slist, out);
}

// Round 2
// 186.022 us; speedup vs baseline: 2.3759x; 2.3759x over previous
//
#include <hip/hip_runtime.h>
#include <hip/hip_bf16.h>
#include <math.h>

#define LTOK 512
#define DDIM 512
#define NEXP 32
#define HDIM 512

typedef __attribute__((ext_vector_type(8))) short short8;
typedef __attribute__((ext_vector_type(4))) float floatx4;

// round-to-nearest-even fp32->bf16, packed pair: low16 = rne(a), high16 = rne(b)
__device__ __forceinline__ unsigned bpack(float a, float b) {
    unsigned ua = __float_as_uint(a), ub = __float_as_uint(b);
    ua += 0x7FFFu + ((ua >> 16) & 1u);
    ub += 0x7FFFu + ((ub >> 16) & 1u);
    return (ua >> 16) | (ub & 0xFFFF0000u);
}

// ws layout (bytes):
//   [0,128)            cnt: 32 ints
//   [256, +64K)        alist: 32*512 ints  (assignment id = 2*token+k)
//   [65792, +64K)      slist: 32*512 floats (routing weight * per_expert_scale)
//   [131328, +512K)    xb: 512x512 bf16 (x rounded to bf16)
//   [655616, +1M)      act: 1024x512 bf16
// total ~1.7 MB

__global__ __launch_bounds__(64) void router_kernel(
    const float* __restrict__ x, const float* __restrict__ rs,
    const float* __restrict__ Wr, const float* __restrict__ pes,
    int* __restrict__ cnt, int* __restrict__ alist, float* __restrict__ slist,
    short* __restrict__ xb)
{
    const int t = blockIdx.x;
    const int lane = threadIdx.x;

    float xv[8];
    float ss = 0.f;
#pragma unroll
    for (int j = 0; j < 8; ++j) {
        xv[j] = x[t * DDIM + j * 64 + lane];
        ss += xv[j] * xv[j];
    }
    // emit bf16 copy of x for the expert GEMMs
#pragma unroll
    for (int j = 0; j < 8; ++j)
        xb[t * DDIM + j * 64 + lane] = (short)(bpack(xv[j], 0.f) & 0xFFFFu);

#pragma unroll
    for (int o = 32; o > 0; o >>= 1) ss += __shfl_xor(ss, o);
    const float var = ss * (1.0f / 512.0f);
    const float coef = rsqrtf(var + 1e-6f) * rsqrtf(512.0f);

    __shared__ float ri[DDIM];
#pragma unroll
    for (int j = 0; j < 8; ++j) {
        const int d = j * 64 + lane;
        ri[d] = xv[j] * coef * rs[d];
    }
    __syncthreads();

    // logits: lane&31 -> expert, lane>>5 -> half of D
    const int e = lane & 31;
    const int half = lane >> 5;
    float lg = 0.f;
    const int dbeg = half * 256;
#pragma unroll 4
    for (int d = dbeg; d < dbeg + 256; ++d)
        lg = fmaf(ri[d], Wr[d * NEXP + e], lg);
    lg += __shfl_xor(lg, 32);

    __shared__ float lgs[NEXP];
    if (lane < 32) lgs[lane] = lg;
    __syncthreads();

    if (lane == 0) {
        int i0 = 0; float m0 = lgs[0];
        for (int i = 1; i < NEXP; ++i) if (lgs[i] > m0) { m0 = lgs[i]; i0 = i; }
        int i1 = -1; float m1 = -1e30f;
        for (int i = 0; i < NEXP; ++i) if (i != i0 && lgs[i] > m1) { m1 = lgs[i]; i1 = i; }
        // softmax denom cancels against renorm: weights depend only on top-2 logits
        const float e1 = expf(m1 - m0);
        const float inv = 1.0f / (1.0f + e1);
        const float w0 = inv, w1 = e1 * inv;

        int p0 = atomicAdd(&cnt[i0], 1);
        alist[i0 * LTOK + p0] = t * 2;
        slist[i0 * LTOK + p0] = w0 * pes[i0];
        int p1 = atomicAdd(&cnt[i1], 1);
        alist[i1 * LTOK + p1] = t * 2 + 1;
        slist[i1 * LTOK + p1] = w1 * pes[i1];
    }
}

// grid (32, 32): blockIdx.x = 16-wide h tile, blockIdx.y = expert.
// 2 waves: wave0 computes gate0, wave1 computes gate1; LDS exchange at epilogue.
// MFMA 16x16x32 bf16. A frag: lane holds A[m=lane&15][k=quad*8+j] (8 consec k).
// B frag: lane holds B[k=quad*8+j][n=lane&15] = G[h0+n][k..], 8 consec d -> direct global load.
__global__ __launch_bounds__(128, 1) void gates_kernel(
    const short* __restrict__ xb, const float* __restrict__ G,
    const int* __restrict__ cnt, const int* __restrict__ alist,
    short* __restrict__ act)
{
    const int e  = blockIdx.y;
    const int h0 = blockIdx.x * 16;
    const int Ne = cnt[e];
    if (Ne == 0) return;
    const int wv   = threadIdx.x >> 6;   // gate index 0/1
    const int lane = threadIdx.x & 63;
    const int n    = lane & 15;
    const int quad = lane >> 4;

    __shared__ float xch[4][4][64];

    const float* Grow = G + ((size_t)((e * 2 + wv) * HDIM) + h0 + n) * DDIM;
    const int* al = alist + e * LTOK;

    for (int mb = 0; mb < Ne; mb += 64) {
        int arow[4];
#pragma unroll
        for (int i = 0; i < 4; ++i) {
            int s = mb + i * 16 + n;
            arow[i] = al[s < Ne ? s : Ne - 1] >> 1;   // token index
        }
        floatx4 acc[4] = {};

#pragma unroll 4
        for (int ks = 0; ks < 16; ++ks) {
            const int ko = ks * 32 + quad * 8;
            const floatx4 b0 = *(const floatx4*)(Grow + ko);
            const floatx4 b1 = *(const floatx4*)(Grow + ko + 4);
            union { short8 s; unsigned u[4]; } B;
            B.u[0] = bpack(b0.x, b0.y);
            B.u[1] = bpack(b0.z, b0.w);
            B.u[2] = bpack(b1.x, b1.y);
            B.u[3] = bpack(b1.z, b1.w);
#pragma unroll
            for (int i = 0; i < 4; ++i) {
                const short8 A = *(const short8*)(xb + (size_t)arow[i] * DDIM + ko);
                acc[i] = __builtin_amdgcn_mfma_f32_16x16x32_bf16(A, B.s, acc[i], 0, 0, 0);
            }
        }

        if (wv == 0) {
#pragma unroll
            for (int i = 0; i < 4; ++i)
#pragma unroll
                for (int r = 0; r < 4; ++r)
                    xch[i][r][lane] = acc[i][r];
        }
        __syncthreads();
        if (wv == 1) {
            // C/D layout: col = lane&15 (h), row = quad*4 + r (token slot)
#pragma unroll
            for (int i = 0; i < 4; ++i) {
#pragma unroll
                for (int r = 0; r < 4; ++r) {
                    const int s = mb + i * 16 + quad * 4 + r;
                    if (s < Ne) {
                        const int a = al[s];
                        const float g0 = xch[i][r][lane];
                        const float g1 = acc[i][r];
                        // gelu_tanh(g0) = g0 * sigmoid(2*u)
                        const float u = 0.7978845608f * (g0 + 0.044715f * g0 * g0 * g0);
                        const float sg = 1.0f / (1.0f + __expf(-2.0f * u));
                        const float v = g0 * sg * g1;
                        act[(size_t)a * HDIM + h0 + n] = (short)(bpack(v, 0.f) & 0xFFFFu);
                    }
                }
            }
        }
        __syncthreads();
    }
}

// grid (32, 32): blockIdx.x = 16-wide d tile, blockIdx.y = expert. 1 wave.
// B[k=h][n=d] = Wl[e][h][d0+n]: 8 strided dword loads; across the 16 n-lanes each
// instr reads 4 rows x 64B fully-used segments (no over-fetch).
__global__ __launch_bounds__(64, 1) void linear_kernel(
    const short* __restrict__ act, const float* __restrict__ Wl,
    const int* __restrict__ cnt, const int* __restrict__ alist,
    const float* __restrict__ slist, float* __restrict__ out)
{
    const int e  = blockIdx.y;
    const int d0 = blockIdx.x * 16;
    const int Ne = cnt[e];
    if (Ne == 0) return;
    const int lane = threadIdx.x;
    const int n    = lane & 15;
    const int quad = lane >> 4;

    const float* Wcol = Wl + (size_t)e * HDIM * DDIM + d0 + n;
    const int* al = alist + e * LTOK;
    const float* sl = slist + e * LTOK;

    for (int mb = 0; mb < Ne; mb += 64) {
        int arow[4];
#pragma unroll
        for (int i = 0; i < 4; ++i) {
            int s = mb + i * 16 + n;
            arow[i] = al[s < Ne ? s : Ne - 1];   // assignment id = act row
        }
        floatx4 acc[4] = {};

#pragma unroll 2
        for (int ks = 0; ks < 16; ++ks) {
            const int ko = ks * 32 + quad * 8;
            float w[8];
#pragma unroll
            for (int j = 0; j < 8; ++j)
                w[j] = Wcol[(size_t)(ko + j) * DDIM];
            union { short8 s; unsigned u[4]; } B;
            B.u[0] = bpack(w[0], w[1]);
            B.u[1] = bpack(w[2], w[3]);
            B.u[2] = bpack(w[4], w[5]);
            B.u[3] = bpack(w[6], w[7]);
#pragma unroll
            for (int i = 0; i < 4; ++i) {
                const short8 A = *(const short8*)(act + (size_t)arow[i] * HDIM + ko);
                acc[i] = __builtin_amdgcn_mfma_f32_16x16x32_bf16(A, B.s, acc[i], 0, 0, 0);
            }
        }

#pragma unroll
        for (int i = 0; i < 4; ++i) {
#pragma unroll
            for (int r = 0; r < 4; ++r) {
                const int s = mb + i * 16 + quad * 4 + r;
                if (s < Ne) {
                    const int a = al[s];
                    atomicAdd(&out[(size_t)(a >> 1) * DDIM + d0 + n], acc[i][r] * sl[s]);
                }
            }
        }
    }
}

extern "C" void kernel_launch(void* const* d_in, const int* in_sizes, int n_in,
                              void* d_out, int out_size, void* d_ws, size_t ws_size,
                              hipStream_t stream)
{
    const float* x   = (const float*)d_in[0];
    const float* rs  = (const float*)d_in[1];
    const float* Wr  = (const float*)d_in[2];
    const float* G   = (const float*)d_in[3];
    const float* Wl  = (const float*)d_in[4];
    const float* pes = (const float*)d_in[5];
    float* out = (float*)d_out;

    char* ws = (char*)d_ws;
    int*   cnt   = (int*)(ws);
    int*   alist = (int*)(ws + 256);
    float* slist = (float*)(ws + 256 + 65536);
    short* xb    = (short*)(ws + 131328);
    short* act   = (short*)(ws + 655616);

    hipMemsetAsync(cnt, 0, NEXP * sizeof(int), stream);
    hipMemsetAsync(out, 0, (size_t)out_size * sizeof(float), stream);

    router_kernel<<<dim3(LTOK), dim3(64), 0, stream>>>(x, rs, Wr, pes, cnt, alist, slist, xb);
    gates_kernel<<<dim3(32, NEXP), dim3(128), 0, stream>>>(xb, G, cnt, alist, act);
    linear_kernel<<<dim3(32, NEXP), dim3(64), 0, stream>>>(act, Wl, cnt, alist, slist, out);
}

// Round 3
// 165.360 us; speedup vs baseline: 2.6728x; 1.1250x over previous
//
#include <hip/hip_runtime.h>
#include <hip/hip_bf16.h>
#include <math.h>

#define LTOK 512
#define DDIM 512
#define NEXP 32
#define HDIM 512

typedef __attribute__((ext_vector_type(8))) short short8;
typedef __attribute__((ext_vector_type(4))) float floatx4;

// round-to-nearest-even fp32->bf16, packed pair: low16 = rne(a), high16 = rne(b)
__device__ __forceinline__ unsigned bpack(float a, float b) {
    unsigned ua = __float_as_uint(a), ub = __float_as_uint(b);
    ua += 0x7FFFu + ((ua >> 16) & 1u);
    ub += 0x7FFFu + ((ub >> 16) & 1u);
    return (ua >> 16) | (ub & 0xFFFF0000u);
}

// ws layout (bytes):
//   [0,128)            cnt: 32 ints
//   [256, +64K)        alist: 32*512 ints  (assignment id = 2*token+k)
//   [65792, +64K)      slist: 32*512 floats (routing weight * per_expert_scale)
//   [131328, +512K)    xb: 512x512 bf16 (x rounded to bf16)
//   [655616, +1M)      act: 1024x512 bf16
// total ~1.7 MB

__global__ __launch_bounds__(64) void router_kernel(
    const float* __restrict__ x, const float* __restrict__ rs,
    const float* __restrict__ Wr, const float* __restrict__ pes,
    int* __restrict__ cnt, int* __restrict__ alist, float* __restrict__ slist,
    short* __restrict__ xb)
{
    const int t = blockIdx.x;
    const int lane = threadIdx.x;

    float xv[8];
    float ss = 0.f;
#pragma unroll
    for (int j = 0; j < 8; ++j) {
        xv[j] = x[t * DDIM + j * 64 + lane];
        ss += xv[j] * xv[j];
    }
    // emit bf16 copy of x for the expert GEMMs
#pragma unroll
    for (int j = 0; j < 8; ++j)
        xb[t * DDIM + j * 64 + lane] = (short)(bpack(xv[j], 0.f) & 0xFFFFu);

#pragma unroll
    for (int o = 32; o > 0; o >>= 1) ss += __shfl_xor(ss, o);
    const float var = ss * (1.0f / 512.0f);
    const float coef = rsqrtf(var + 1e-6f) * rsqrtf(512.0f);

    __shared__ float ri[DDIM];
#pragma unroll
    for (int j = 0; j < 8; ++j) {
        const int d = j * 64 + lane;
        ri[d] = xv[j] * coef * rs[d];
    }
    __syncthreads();

    // logits: lane&31 -> expert, lane>>5 -> half of D; 4 partial accs break the chain
    const int e = lane & 31;
    const int half = lane >> 5;
    const int dbeg = half * 256;
    float l0 = 0.f, l1 = 0.f, l2 = 0.f, l3 = 0.f;
#pragma unroll 4
    for (int d = dbeg; d < dbeg + 256; d += 4) {
        l0 = fmaf(ri[d + 0], Wr[(d + 0) * NEXP + e], l0);
        l1 = fmaf(ri[d + 1], Wr[(d + 1) * NEXP + e], l1);
        l2 = fmaf(ri[d + 2], Wr[(d + 2) * NEXP + e], l2);
        l3 = fmaf(ri[d + 3], Wr[(d + 3) * NEXP + e], l3);
    }
    float lg = (l0 + l1) + (l2 + l3);
    lg += __shfl_xor(lg, 32);

    __shared__ float lgs[NEXP];
    if (lane < 32) lgs[lane] = lg;
    __syncthreads();

    if (lane == 0) {
        int i0 = 0; float m0 = lgs[0];
        for (int i = 1; i < NEXP; ++i) if (lgs[i] > m0) { m0 = lgs[i]; i0 = i; }
        int i1 = -1; float m1 = -1e30f;
        for (int i = 0; i < NEXP; ++i) if (i != i0 && lgs[i] > m1) { m1 = lgs[i]; i1 = i; }
        // softmax denom cancels against renorm: weights depend only on top-2 logits
        const float e1 = expf(m1 - m0);
        const float inv = 1.0f / (1.0f + e1);
        const float w0 = inv, w1 = e1 * inv;

        int p0 = atomicAdd(&cnt[i0], 1);
        alist[i0 * LTOK + p0] = t * 2;
        slist[i0 * LTOK + p0] = w0 * pes[i0];
        int p1 = atomicAdd(&cnt[i1], 1);
        alist[i1 * LTOK + p1] = t * 2 + 1;
        slist[i1 * LTOK + p1] = w1 * pes[i1];
    }
}

// grid (32, 32): blockIdx.x = 16-wide h tile, blockIdx.y = expert.
// 4 waves: wv = (khalf<<1) | gate. Each wave streams K/2=256 of its gate's rows,
// partials reduced through LDS, all 4 waves share the epilogue (one m-tile each).
// MFMA 16x16x32 bf16. A: lane holds A[m=lane&15][k=quad*8+j]; B: 8 consec d from G row.
__global__ __launch_bounds__(256, 4) void gates_kernel(
    const short* __restrict__ xb, const float* __restrict__ G,
    const int* __restrict__ cnt, const int* __restrict__ alist,
    short* __restrict__ act)
{
    const int e  = blockIdx.y;
    const int h0 = blockIdx.x * 16;
    const int Ne = cnt[e];
    if (Ne == 0) return;
    const int wv   = threadIdx.x >> 6;
    const int g    = wv & 1;    // gate index
    const int kh   = wv >> 1;   // K half
    const int lane = threadIdx.x & 63;
    const int n    = lane & 15;
    const int quad = lane >> 4;

    __shared__ float red[4][4][4][64];   // [wave][m-tile][reg][lane] = 16 KB

    const float* Grow = G + ((size_t)((e * 2 + g) * HDIM) + h0 + n) * DDIM + kh * 256;
    const short* xbh  = xb + kh * 256;
    const int* al = alist + e * LTOK;

    for (int mb = 0; mb < Ne; mb += 64) {
        int arow[4];
#pragma unroll
        for (int i = 0; i < 4; ++i) {
            int s = mb + i * 16 + n;
            arow[i] = al[s < Ne ? s : Ne - 1] >> 1;   // token index
        }
        floatx4 acc[4] = {};

#pragma unroll 4
        for (int ks = 0; ks < 8; ++ks) {
            const int ko = ks * 32 + quad * 8;
            const floatx4 b0 = *(const floatx4*)(Grow + ko);
            const floatx4 b1 = *(const floatx4*)(Grow + ko + 4);
            union { short8 s; unsigned u[4]; } B;
            B.u[0] = bpack(b0.x, b0.y);
            B.u[1] = bpack(b0.z, b0.w);
            B.u[2] = bpack(b1.x, b1.y);
            B.u[3] = bpack(b1.z, b1.w);
#pragma unroll
            for (int i = 0; i < 4; ++i) {
                const short8 A = *(const short8*)(xbh + (size_t)arow[i] * DDIM + ko);
                acc[i] = __builtin_amdgcn_mfma_f32_16x16x32_bf16(A, B.s, acc[i], 0, 0, 0);
            }
        }

#pragma unroll
        for (int i = 0; i < 4; ++i)
#pragma unroll
            for (int r = 0; r < 4; ++r)
                red[wv][i][r][lane] = acc[i][r];
        __syncthreads();

        // epilogue: wave wv handles m-tile wv. C/D: col = lane&15, row = quad*4+r.
        {
            const int i = wv;
#pragma unroll
            for (int r = 0; r < 4; ++r) {
                const int s = mb + i * 16 + quad * 4 + r;
                if (s < Ne) {
                    const int a = al[s];
                    const float g0 = red[0][i][r][lane] + red[2][i][r][lane];
                    const float g1 = red[1][i][r][lane] + red[3][i][r][lane];
                    // gelu_tanh(g0) = g0 * sigmoid(2*u)
                    const float u = 0.7978845608f * (g0 + 0.044715f * g0 * g0 * g0);
                    const float sg = 1.0f / (1.0f + __expf(-2.0f * u));
                    const float v = g0 * sg * g1;
                    act[(size_t)a * HDIM + h0 + n] = (short)(bpack(v, 0.f) & 0xFFFFu);
                }
            }
        }
        __syncthreads();
    }
}

// grid (32, 32): blockIdx.x = 16-wide d tile, blockIdx.y = expert.
// 4 waves = K quarters (128 h each); LDS reduction; wave wv does m-tile wv epilogue.
__global__ __launch_bounds__(256, 4) void linear_kernel(
    const short* __restrict__ act, const float* __restrict__ Wl,
    const int* __restrict__ cnt, const int* __restrict__ alist,
    const float* __restrict__ slist, float* __restrict__ out)
{
    const int e  = blockIdx.y;
    const int d0 = blockIdx.x * 16;
    const int Ne = cnt[e];
    if (Ne == 0) return;
    const int wv   = threadIdx.x >> 6;
    const int lane = threadIdx.x & 63;
    const int n    = lane & 15;
    const int quad = lane >> 4;

    __shared__ float red[4][4][4][64];   // 16 KB

    const float* Wcol = Wl + (size_t)e * HDIM * DDIM + d0 + n;
    const int* al = alist + e * LTOK;
    const float* sl = slist + e * LTOK;

    for (int mb = 0; mb < Ne; mb += 64) {
        int arow[4];
#pragma unroll
        for (int i = 0; i < 4; ++i) {
            int s = mb + i * 16 + n;
            arow[i] = al[s < Ne ? s : Ne - 1];   // assignment id = act row
        }
        floatx4 acc[4] = {};

#pragma unroll 2
        for (int ks = 0; ks < 4; ++ks) {
            const int ko = wv * 128 + ks * 32 + quad * 8;
            float w[8];
#pragma unroll
            for (int j = 0; j < 8; ++j)
                w[j] = Wcol[(size_t)(ko + j) * DDIM];
            union { short8 s; unsigned u[4]; } B;
            B.u[0] = bpack(w[0], w[1]);
            B.u[1] = bpack(w[2], w[3]);
            B.u[2] = bpack(w[4], w[5]);
            B.u[3] = bpack(w[6], w[7]);
#pragma unroll
            for (int i = 0; i < 4; ++i) {
                const short8 A = *(const short8*)(act + (size_t)arow[i] * HDIM + ko);
                acc[i] = __builtin_amdgcn_mfma_f32_16x16x32_bf16(A, B.s, acc[i], 0, 0, 0);
            }
        }

#pragma unroll
        for (int i = 0; i < 4; ++i)
#pragma unroll
            for (int r = 0; r < 4; ++r)
                red[wv][i][r][lane] = acc[i][r];
        __syncthreads();

        {
            const int i = wv;
#pragma unroll
            for (int r = 0; r < 4; ++r) {
                const int s = mb + i * 16 + quad * 4 + r;
                if (s < Ne) {
                    const int a = al[s];
                    const float v = ((red[0][i][r][lane] + red[1][i][r][lane]) +
                                     (red[2][i][r][lane] + red[3][i][r][lane])) * sl[s];
                    atomicAdd(&out[(size_t)(a >> 1) * DDIM + d0 + n], v);
                }
            }
        }
        __syncthreads();
    }
}

extern "C" void kernel_launch(void* const* d_in, const int* in_sizes, int n_in,
                              void* d_out, int out_size, void* d_ws, size_t ws_size,
                              hipStream_t stream)
{
    const float* x   = (const float*)d_in[0];
    const float* rs  = (const float*)d_in[1];
    const float* Wr  = (const float*)d_in[2];
    const float* G   = (const float*)d_in[3];
    const float* Wl  = (const float*)d_in[4];
    const float* pes = (const float*)d_in[5];
    float* out = (float*)d_out;

    char* ws = (char*)d_ws;
    int*   cnt   = (int*)(ws);
    int*   alist = (int*)(ws + 256);
    float* slist = (float*)(ws + 256 + 65536);
    short* xb    = (short*)(ws + 131328);
    short* act   = (short*)(ws + 655616);

    hipMemsetAsync(cnt, 0, NEXP * sizeof(int), stream);
    hipMemsetAsync(out, 0, (size_t)out_size * sizeof(float), stream);

    router_kernel<<<dim3(LTOK), dim3(64), 0, stream>>>(x, rs, Wr, pes, cnt, alist, slist, xb);
    gates_kernel<<<dim3(32, NEXP), dim3(256), 0, stream>>>(xb, G, cnt, alist, act);
    linear_kernel<<<dim3(32, NEXP), dim3(256), 0, stream>>>(act, Wl, cnt, alist, slist, out);
}